// Round 1
// baseline (68.776 us; speedup 1.0000x reference)
//
#include <hip/hip_runtime.h>
#include <math.h>

#define BLK 256
#define MAXF 1024   // max supported frequency-bin count; F = 201 here. ws usage = 2*MAXF*4 = 8 KB

// Kernel 1: per-frequency DFT projection.
// real[j] = sum_i x[i] * cos(2*pi*(fmin+j)*i/fs), imag[j] = ... sin(...)
// Exact integer angle reduction: k = (f*i) mod fs, ang = (2*pi/fs)*k in [0, 2pi).
__global__ void __launch_bounds__(BLK) dft_proj_kernel(
    const float* __restrict__ x, int N,
    const int* __restrict__ p_fs,
    const int* __restrict__ p_fmin,
    const int* __restrict__ p_fmax,
    float* __restrict__ ws)
{
    const unsigned fs   = (unsigned)*p_fs;
    const int      fmin = *p_fmin;
    const int      fmax = *p_fmax;
    const int      F    = fmax - fmin + 1;
    const float c = (float)(6.283185307179586 / (double)fs);

    __shared__ float red[8];  // 4 waves x {re, im}

    for (int j = blockIdx.x; j < F && j < MAXF; j += gridDim.x) {
        const unsigned f   = (unsigned)(fmin + j);
        const int      tid = threadIdx.x;

        // k = (f * i) mod fs, maintained incrementally with step = (f*BLK) mod fs
        unsigned k          = (unsigned)(((unsigned long long)f * (unsigned)tid) % fs);
        const unsigned step = (unsigned)(((unsigned long long)f * (unsigned)BLK) % fs);

        float ar = 0.0f, ai = 0.0f;
        for (int i = tid; i < N; i += BLK) {
            float ang = c * (float)k;          // in [0, 2pi), well-conditioned
            float s, cc;
            sincosf(ang, &s, &cc);
            float xv = x[i];
            ar = fmaf(xv, cc, ar);
            ai = fmaf(xv, s,  ai);
            k += step;
            if (k >= fs) k -= fs;
        }

        // wave (64-lane) butterfly reduce
        #pragma unroll
        for (int o = 32; o > 0; o >>= 1) {
            ar += __shfl_down(ar, o, 64);
            ai += __shfl_down(ai, o, 64);
        }
        const int lane = tid & 63;
        const int wid  = tid >> 6;
        if (lane == 0) { red[wid * 2] = ar; red[wid * 2 + 1] = ai; }
        __syncthreads();
        if (tid == 0) {
            float r  = red[0] + red[2] + red[4] + red[6];
            float im = red[1] + red[3] + red[5] + red[7];
            ws[j]        = r;
            ws[MAXF + j] = im;
        }
        __syncthreads();  // protect red[] before next grid-stride iteration
    }
}

// Kernel 2: psd = re^2 + im^2; split wanted/unwanted; loss = -10*log10(t1/t2)
__global__ void __launch_bounds__(BLK) loss_kernel(
    const float* __restrict__ ws,
    const int* __restrict__ p_ftrue,
    const int* __restrict__ p_delta,
    const int* __restrict__ p_fmin,
    const int* __restrict__ p_fmax,
    float* __restrict__ out)
{
    const int ftrue = *p_ftrue;
    const int delta = *p_delta;
    const int fmin  = *p_fmin;
    const int fmax  = *p_fmax;
    const int F     = fmax - fmin + 1;

    float t1 = 0.0f, t2 = 0.0f;
    for (int j = threadIdx.x; j < F && j < MAXF; j += BLK) {
        float r   = ws[j];
        float im  = ws[MAXF + j];
        float psd = r * r + im * im;
        int   f   = fmin + j;
        bool wanted = (f >= ftrue - delta) && (f <= ftrue + delta);
        if (wanted) t1 += psd; else t2 += psd;
    }

    __shared__ float red[8];
    #pragma unroll
    for (int o = 32; o > 0; o >>= 1) {
        t1 += __shfl_down(t1, o, 64);
        t2 += __shfl_down(t2, o, 64);
    }
    const int lane = threadIdx.x & 63;
    const int wid  = threadIdx.x >> 6;
    if (lane == 0) { red[wid * 2] = t1; red[wid * 2 + 1] = t2; }
    __syncthreads();
    if (threadIdx.x == 0) {
        float a = red[0] + red[2] + red[4] + red[6];
        float b = red[1] + red[3] + red[5] + red[7];
        out[0] = -10.0f * log10f(a / b);
    }
}

extern "C" void kernel_launch(void* const* d_in, const int* in_sizes, int n_in,
                              void* d_out, int out_size, void* d_ws, size_t ws_size,
                              hipStream_t stream) {
    const float* x       = (const float*)d_in[0];
    const int*   p_ftrue = (const int*)d_in[1];
    const int*   p_fs    = (const int*)d_in[2];
    const int*   p_delta = (const int*)d_in[3];
    const int*   p_fmin  = (const int*)d_in[4];
    const int*   p_fmax  = (const int*)d_in[5];
    float*       out     = (float*)d_out;
    float*       ws      = (float*)d_ws;
    const int N = in_sizes[0];

    // F is only known on device; 256 grid-strided blocks cover any F <= MAXF
    // (F = 201 here -> ~1 freq/block, one block per CU).
    dft_proj_kernel<<<256, BLK, 0, stream>>>(x, N, p_fs, p_fmin, p_fmax, ws);
    loss_kernel<<<1, BLK, 0, stream>>>(ws, p_ftrue, p_delta, p_fmin, p_fmax, out);
}

// Round 2
// 16.597 us; speedup vs baseline: 4.1438x; 4.1438x over previous
//
#include <hip/hip_runtime.h>
#include <math.h>

#define BLK   256
#define MAXF  512     // max frequency bins supported (F = 201 here)
#define SPLIT 8       // chunks per frequency -> F*SPLIT blocks of work
#define ILP   4       // independent accumulator/recurrence lanes per thread
// ws layout: [MAXF*SPLIT] real partials, then [MAXF*SPLIT] imag partials = 32 KB

// Kernel 1: per-(frequency, chunk) partial DFT projection.
// Exact integer angle: k = (f*i) mod fs; rev = k/fs in [0,1);
// v_sin_f32/v_cos_f32 take revolutions directly -> no range reduction at all.
__global__ void __launch_bounds__(BLK) dft_proj_kernel(
    const float* __restrict__ x, int N,
    const int* __restrict__ p_fs,
    const int* __restrict__ p_fmin,
    const int* __restrict__ p_fmax,
    float* __restrict__ ws)
{
    const unsigned fs   = (unsigned)*p_fs;
    const int      fmin = *p_fmin;
    const int      fmax = *p_fmax;
    const int      F    = fmax - fmin + 1;
    const float  inv_fs = 1.0f / (float)fs;

    const int Nc = (N + SPLIT - 1) / SPLIT;   // elements per chunk
    const int W  = F * SPLIT;                 // total work items

    __shared__ float red[8];  // 4 waves x {re, im}

    for (int w = blockIdx.x; w < W; w += gridDim.x) {
        const int j     = w >> 3;             // w / SPLIT (SPLIT == 8)
        const int chunk = w & (SPLIT - 1);
        if (j >= MAXF) break;

        const unsigned f   = (unsigned)(fmin + j);
        const int      tid = threadIdx.x;
        const int      i0  = chunk * Nc + tid;
        const int      iend = min(N, (chunk + 1) * Nc);

        const unsigned long long f64 = (unsigned long long)f;
        unsigned k[ILP];
        #pragma unroll
        for (int u = 0; u < ILP; ++u)
            k[u] = (unsigned)((f64 * (unsigned long long)(unsigned)(i0 + u * BLK)) % fs);
        const unsigned stepL = (unsigned)((f64 * (unsigned long long)(ILP * BLK)) % fs);

        float ar[ILP], ai[ILP];
        #pragma unroll
        for (int u = 0; u < ILP; ++u) { ar[u] = 0.0f; ai[u] = 0.0f; }

        int i = i0;
        // main loop: all ILP elements in-bounds
        for (; i + (ILP - 1) * BLK < iend; i += ILP * BLK) {
            #pragma unroll
            for (int u = 0; u < ILP; ++u) {
                float rev = (float)k[u] * inv_fs;        // [0,1)
                float s  = __builtin_amdgcn_sinf(rev);   // sin(2*pi*rev)
                float cc = __builtin_amdgcn_cosf(rev);   // cos(2*pi*rev)
                float xv = x[i + u * BLK];
                ar[u] = fmaf(xv, cc, ar[u]);
                ai[u] = fmaf(xv, s,  ai[u]);
                k[u] += stepL;
                if (k[u] >= fs) k[u] -= fs;
            }
        }
        // tail: at most one pass with per-element guards
        #pragma unroll
        for (int u = 0; u < ILP; ++u) {
            int idx = i + u * BLK;
            if (idx < iend) {
                float rev = (float)k[u] * inv_fs;
                float s  = __builtin_amdgcn_sinf(rev);
                float cc = __builtin_amdgcn_cosf(rev);
                float xv = x[idx];
                ar[u] = fmaf(xv, cc, ar[u]);
                ai[u] = fmaf(xv, s,  ai[u]);
            }
        }

        float arS = (ar[0] + ar[1]) + (ar[2] + ar[3]);
        float aiS = (ai[0] + ai[1]) + (ai[2] + ai[3]);

        // wave butterfly reduce (64 lanes)
        #pragma unroll
        for (int o = 32; o > 0; o >>= 1) {
            arS += __shfl_down(arS, o, 64);
            aiS += __shfl_down(aiS, o, 64);
        }
        const int lane = tid & 63;
        const int wid  = tid >> 6;
        if (lane == 0) { red[wid * 2] = arS; red[wid * 2 + 1] = aiS; }
        __syncthreads();
        if (tid == 0) {
            ws[w]                = (red[0] + red[2]) + (red[4] + red[6]);
            ws[MAXF * SPLIT + w] = (red[1] + red[3]) + (red[5] + red[7]);
        }
        __syncthreads();  // protect red[] before next grid-stride iteration
    }
}

// Kernel 2: fold SPLIT partials per freq, psd, band split, loss.
__global__ void __launch_bounds__(BLK) loss_kernel(
    const float* __restrict__ ws,
    const int* __restrict__ p_ftrue,
    const int* __restrict__ p_delta,
    const int* __restrict__ p_fmin,
    const int* __restrict__ p_fmax,
    float* __restrict__ out)
{
    const int ftrue = *p_ftrue;
    const int delta = *p_delta;
    const int fmin  = *p_fmin;
    const int fmax  = *p_fmax;
    const int F     = fmax - fmin + 1;

    float t1 = 0.0f, t2 = 0.0f;
    for (int j = threadIdx.x; j < F && j < MAXF; j += BLK) {
        float r = 0.0f, im = 0.0f;
        #pragma unroll
        for (int u = 0; u < SPLIT; ++u) {
            r  += ws[j * SPLIT + u];
            im += ws[MAXF * SPLIT + j * SPLIT + u];
        }
        float psd = r * r + im * im;
        int   f   = fmin + j;
        bool wanted = (f >= ftrue - delta) && (f <= ftrue + delta);
        if (wanted) t1 += psd; else t2 += psd;
    }

    __shared__ float red[8];
    #pragma unroll
    for (int o = 32; o > 0; o >>= 1) {
        t1 += __shfl_down(t1, o, 64);
        t2 += __shfl_down(t2, o, 64);
    }
    const int lane = threadIdx.x & 63;
    const int wid  = threadIdx.x >> 6;
    if (lane == 0) { red[wid * 2] = t1; red[wid * 2 + 1] = t2; }
    __syncthreads();
    if (threadIdx.x == 0) {
        float a = (red[0] + red[2]) + (red[4] + red[6]);
        float b = (red[1] + red[3]) + (red[5] + red[7]);
        out[0] = -10.0f * log10f(a / b);
    }
}

extern "C" void kernel_launch(void* const* d_in, const int* in_sizes, int n_in,
                              void* d_out, int out_size, void* d_ws, size_t ws_size,
                              hipStream_t stream) {
    const float* x       = (const float*)d_in[0];
    const int*   p_ftrue = (const int*)d_in[1];
    const int*   p_fs    = (const int*)d_in[2];
    const int*   p_delta = (const int*)d_in[3];
    const int*   p_fmin  = (const int*)d_in[4];
    const int*   p_fmax  = (const int*)d_in[5];
    float*       out     = (float*)d_out;
    float*       ws      = (float*)d_ws;
    const int N = in_sizes[0];

    // F known only on device; 2048 grid-strided blocks cover F*SPLIT <= 4096
    // (F=201 -> 1608 live blocks ~ 6/CU ~ 24 waves/CU).
    dft_proj_kernel<<<2048, BLK, 0, stream>>>(x, N, p_fs, p_fmin, p_fmax, ws);
    loss_kernel<<<1, BLK, 0, stream>>>(ws, p_ftrue, p_delta, p_fmin, p_fmax, out);
}